// Round 17
// baseline (1030.352 us; speedup 1.0000x reference)
//
#include <hip/hip_runtime.h>

typedef _Float16 half8 __attribute__((ext_vector_type(8)));
typedef float floatx4 __attribute__((ext_vector_type(4)));

#define DEV_INLINE __device__ __forceinline__

constexpr int D0 = 512, D1 = 256, D2 = 256, D3 = 128;
constexpr int NROWS = 16384;
constexpr int MBLK = 32;            // batch rows per block
constexpr int NBLK = NROWS / MBLK;  // 512 blocks
constexpr int KITERS = 16;
constexpr float ETA = 0.1f;

// packed-weight element offsets (fp16 elements) inside d_ws
constexpr int OFF_WF0 = 0;                  // fwd W0: K=256, N=512
constexpr int OFF_WF1 = OFF_WF0 + D1 * D0;  // fwd W1: K=256, N=256
constexpr int OFF_WF2 = OFF_WF1 + D2 * D1;  // fwd W2: K=128, N=256
constexpr int OFF_WB0 = OFF_WF2 + D3 * D2;  // bwd W0^T: K=512, N=256
constexpr int OFF_WB1 = OFF_WB0 + D0 * D1;  // bwd W1^T: K=256, N=256
constexpr int OFF_WB2 = OFF_WB1 + D1 * D2;  // bwd W2^T: K=256, N=128
constexpr int PACK_ELEMS = OFF_WB2 + D2 * D3;  // 458752 elems = 896 KB fp16

// ---------------------------------------------------------------------------
// Repack weights into MFMA B-fragment order + cast x0 to fp16 (if ws fits).
// ---------------------------------------------------------------------------
__global__ void repack_kernel(const float* __restrict__ W0, const float* __restrict__ W1,
                              const float* __restrict__ W2, const float* __restrict__ x0,
                              _Float16* __restrict__ pack, _Float16* __restrict__ x0h,
                              int do_x0) {
  int p = blockIdx.x * 256 + threadIdx.x;
  if (p < PACK_ELEMS) {
    const float* W; int Csrc, Nd, off; bool tr;
    if (p < OFF_WF1)      { W = W0; Csrc = D0; Nd = D0; off = OFF_WF0; tr = false; }
    else if (p < OFF_WF2) { W = W1; Csrc = D1; Nd = D1; off = OFF_WF1; tr = false; }
    else if (p < OFF_WB0) { W = W2; Csrc = D2; Nd = D2; off = OFF_WF2; tr = false; }
    else if (p < OFF_WB1) { W = W0; Csrc = D0; Nd = D1; off = OFF_WB0; tr = true;  }
    else if (p < OFF_WB2) { W = W1; Csrc = D1; Nd = D1; off = OFF_WB1; tr = true;  }
    else                  { W = W2; Csrc = D2; Nd = D3; off = OFF_WB2; tr = true;  }
    int local = p - off;
    int j  = local & 7;
    int l  = (local >> 3) & 63;
    int fr = local >> 9;
    int NT = Nd >> 4;
    int nt = fr % NT, kt = fr / NT;
    int k = kt * 32 + ((l >> 4) << 3) + j;
    int n = nt * 16 + (l & 15);
    float v = tr ? W[n * Csrc + k] : W[k * Csrc + n];
    pack[p] = (_Float16)v;
  } else if (do_x0) {
    int q = p - PACK_ELEMS;
    if (q < NROWS * D0) x0h[q] = (_Float16)x0[q];
  }
}

DEV_INLINE float fast_tanh(float x) {
  float e = __expf(2.f * x);                       // v_exp_f32
  return 1.f - 2.f * __builtin_amdgcn_rcpf(e + 1.f);
}

DEV_INLINE const _Float16* bpt(const _Float16* Bp, int nt, int lane) {
  return Bp + ((size_t)nt * 64 + lane) * 8;
}

// ---------------------------------------------------------------------------
// Register-burst matmul: acc[rt*AS+ct] += A(RT*16 x KSTEPS*32) @ B[nt..nt+CT).
// ALL KSTEPS*CT B-tiles (<=8 = 32 VGPR) issued as one burst of ordinary
// global_load_dwordx4; compiler's per-register vmcnt waits pipeline ~8-deep.
// A in LDS, fp16, row stride STRB bytes, XOR-swizzled by ((row&7)<<4).
// ---------------------------------------------------------------------------
template <int RT, int KSTEPS, int CT, int NTT, int STRB, int AS>
DEV_INLINE void mm_burst(const char* __restrict__ A, const _Float16* __restrict__ bsrc,
                         int lane, floatx4* acc) {
  static_assert(KSTEPS * CT <= 8, "bq register budget");
  const int arow = lane & 15;
  const int aoff = (lane >> 4) << 4;  // byte offset of this lane's 16B k-chunk
  half8 bq[KSTEPS * CT];
#pragma unroll
  for (int s = 0; s < KSTEPS; ++s)
#pragma unroll
    for (int ct = 0; ct < CT; ++ct)
      bq[s * CT + ct] = *(const half8*)(bsrc + (size_t)(s * NTT + ct) * 512);
#pragma unroll
  for (int k0 = 0; k0 < KSTEPS; ++k0) {
    half8 a[RT];
#pragma unroll
    for (int rt = 0; rt < RT; ++rt) {
      int row = rt * 16 + arow;
      int byte = (row * STRB + k0 * 64 + aoff) ^ ((row & 7) << 4);
      a[rt] = *(const half8*)(A + byte);
    }
#pragma unroll
    for (int ct = 0; ct < CT; ++ct)
#pragma unroll
      for (int rt = 0; rt < RT; ++rt)
        acc[rt * AS + ct] =
            __builtin_amdgcn_mfma_f32_16x16x32_f16(a[rt], bq[k0 * CT + ct], acc[rt * AS + ct], 0, 0, 0);
  }
}

// ---------------------------------------------------------------------------
// Persistent settling kernel, MBLK=32 rows, 512 threads (8 waves), 56 KB LDS.
// CO-RESIDENCE round: LDS cut to 56 KB (< the 64 KB boundary; NO
// hipFuncSetAttribute) so TWO 512-thread blocks fit per CU (112 KB LDS,
// 16 waves = the 128-VGPR cap) -- every prior config sat at 8 waves/CU and
// each barrier drained the whole CU (149K cy/iter vs ~10K of compute).
// Enabled by PHASE ROTATION: P2 runs FIRST each iter, so the x3 image
// time-shares one 8 KB arena G with the g0-quarters (x3 dead between its
// P2 read and P6ep rewrite; g0 lives only in P3/P4, inside that window).
// LDS (56 KB): AX1[16K]@0: x1[32][256] s512 | G[8K]@16K: x3 image s256
//   <-> g0-quarter s256 | AQ[16K]@24K: x2 s512 | AG1[16K]@40K: g1 s512,
//   then g2 (after B7) for P6.
// Per iter: P2(ep: dx2a,g2h->regs), B1, P1(ep g1->AG1),
//           {P3q(ep->G), B, P4q, B} x4, P4ep->AX1, P5(ep x2 RMW AQ), B7,
//           g2h->AG1, B8, P6, B9, P6ep: x3->G, B10.  13 barriers/iter.
// Every C-cell is owned by exactly one thread -> fp16 RMW in LDS race-free.
// ---------------------------------------------------------------------------
__global__ __launch_bounds__(512)
void settle_kernel(const float* __restrict__ x0,
                   const _Float16* __restrict__ x0h,
                   const _Float16* __restrict__ pack,
                   float* __restrict__ out) {
  extern __shared__ char lds[];
  char* AX1 = lds;
  char* G   = lds + 16384;
  char* AQ  = lds + 24576;
  char* AG1 = lds + 40960;

  const int tid  = threadIdx.x;
  const int lane = tid & 63;
  const int wave = tid >> 6;
  const int row0 = blockIdx.x * MBLK;
  const int rsub = (lane >> 4) << 2;  // C/D layout: row = (lane>>4)*4 + i
  const int csub = lane & 15;         //             col = lane & 15

  // zero-init x2 (AQ, 16K)
  {
    floatx4 z = {0.f, 0.f, 0.f, 0.f};
    for (int i = tid; i < 1024; i += 512) ((floatx4*)AQ)[i] = z;
  }

  const floatx4 zf = {0.f, 0.f, 0.f, 0.f};
  floatx4 x3m[2];  // fp32 master of the output layer [rt]
#pragma unroll
  for (int i = 0; i < 2; ++i) x3m[i] = zf;

  const _Float16* Wf0 = pack + OFF_WF0;
  const _Float16* Wf1 = pack + OFF_WF1;
  const _Float16* Wf2 = pack + OFF_WF2;
  const _Float16* Wb0 = pack + OFF_WB0;
  const _Float16* Wb1 = pack + OFF_WB1;
  const _Float16* Wb2 = pack + OFF_WB2;

  // =================== iteration 0 shortcut ===================
  // all states zero: g0 = x0 (f'(0)=1); only dx1 = x0 @ W0^T is nonzero.
  {
    floatx4 dx1a[4];
#pragma unroll
    for (int i = 0; i < 4; ++i) dx1a[i] = zf;
    for (int q = 0; q < 4; ++q) {
      // stage g0-quarter = x0 cols [q*128, q*128+128) from x0h into G
      for (int idx = tid; idx < MBLK * 128; idx += 512) {
        int row = idx >> 7, colq = idx & 127;
        size_t gi = (size_t)(row0 + row) * D0 + q * 128 + colq;
        _Float16 v = x0h ? x0h[gi] : (_Float16)x0[gi];
        int byte = (row * 256 + colq * 2) ^ ((row & 7) << 4);
        *(_Float16*)(G + byte) = v;
      }
      __syncthreads();  // publish g0 quarter
      mm_burst<2, 4, 2, 16, 256, 2>(G, bpt(Wb0 + q * 32768, wave * 2, lane), lane, dx1a);
      __syncthreads();  // reads done -> G reusable
    }
#pragma unroll
    for (int rt = 0; rt < 2; ++rt)
#pragma unroll
      for (int ct = 0; ct < 2; ++ct) {
        int col = (wave * 2 + ct) * 16 + csub;
#pragma unroll
        for (int i = 0; i < 4; ++i) {
          int row = rt * 16 + rsub + i;
          float dx = fminf(1.f, fmaxf(-1.f, dx1a[rt * 2 + ct][i]));
          int byte = (row * 512 + col * 2) ^ ((row & 7) << 4);
          *(_Float16*)(AX1 + byte) = (_Float16)(ETA * dx);
        }
      }
    // zero the x3 image in G (x3 = 0 entering iteration 1)
    {
      floatx4 z = {0.f, 0.f, 0.f, 0.f};
      for (int i = tid; i < 512; i += 512) ((floatx4*)G)[i] = z;
    }
    __syncthreads();  // publish x1 + x3 image
  }

  // =================== iterations 1..15 (rotated: P2 first) ===================
  for (int it = 1; it < KITERS; ++it) {
    // ---- P2: preact2 = x3 @ W2 (reads G x3 image); ep: dx2a=-e2, g2 -> regs
    floatx4 dx2a[4];
    half8 g2h[2];
    {
      floatx4 p2[4];
#pragma unroll
      for (int i = 0; i < 4; ++i) p2[i] = zf;
      mm_burst<2, 4, 2, 16, 256, 2>(G, bpt(Wf2, wave * 2, lane), lane, p2);
#pragma unroll
      for (int rt = 0; rt < 2; ++rt)
#pragma unroll
        for (int ct = 0; ct < 2; ++ct) {
          int col = (wave * 2 + ct) * 16 + csub;
#pragma unroll
          for (int i = 0; i < 4; ++i) {
            int row = rt * 16 + rsub + i;
            int sb = (row * 512 + col * 2) ^ ((row & 7) << 4);
            float t = fast_tanh(p2[rt * 2 + ct][i]);
            float x2o = (float)*(const _Float16*)(AQ + sb);
            float e = x2o - t;
            int li = (rt * 2 + ct) * 4 + i;
            g2h[li >> 3][li & 7] = (_Float16)(e * (1.f - t * t));
            dx2a[rt * 2 + ct][i] = -e;
          }
        }
    }
    __syncthreads();  // B1: x3 reads done -> G reusable for g0 quarters
    // ---- P1: preact1 = x2 @ W1 (reads AQ); ep: e1, g1 -> AG1, dx1a = -e1
    floatx4 dx1a[4];
    {
#pragma unroll
      for (int i = 0; i < 4; ++i) dx1a[i] = zf;
#pragma unroll
      for (int ct = 0; ct < 2; ++ct)
        mm_burst<2, 8, 1, 16, 512, 2>(AQ, bpt(Wf1, wave * 2 + ct, lane), lane, &dx1a[ct]);
#pragma unroll
      for (int rt = 0; rt < 2; ++rt)
#pragma unroll
        for (int ct = 0; ct < 2; ++ct) {
          int col = (wave * 2 + ct) * 16 + csub;
#pragma unroll
          for (int i = 0; i < 4; ++i) {
            int row = rt * 16 + rsub + i;
            int sb = (row * 512 + col * 2) ^ ((row & 7) << 4);
            float t = fast_tanh(dx1a[rt * 2 + ct][i]);
            float x1o = (float)*(const _Float16*)(AX1 + sb);
            float e = x1o - t;
            *(_Float16*)(AG1 + sb) = (_Float16)(e * (1.f - t * t));
            dx1a[rt * 2 + ct][i] = -e;
          }
        }
    }
    // ---- P3/P4 interleaved over the four K/N=128 quarters of g0 (in G)
    for (int q = 0; q < 4; ++q) {
      {
        floatx4 acc3[2];
#pragma unroll
        for (int i = 0; i < 2; ++i) acc3[i] = zf;
        mm_burst<2, 8, 1, 32, 512, 1>(AX1, bpt(Wf0, q * 8 + wave, lane), lane, acc3);
        int colq = wave * 16 + csub;
#pragma unroll
        for (int rt = 0; rt < 2; ++rt)
#pragma unroll
          for (int i = 0; i < 4; ++i) {
            int row = rt * 16 + rsub + i;
            float t = fast_tanh(acc3[rt][i]);
            size_t gi = (size_t)(row0 + row) * D0 + q * 128 + colq;
            float xv = x0h ? (float)x0h[gi] : x0[gi];
            float g = (xv - t) * (1.f - t * t);
            int byte = (row * 256 + colq * 2) ^ ((row & 7) << 4);
            *(_Float16*)(G + byte) = (_Float16)g;
          }
      }
      __syncthreads();  // publish g0 quarter
      mm_burst<2, 4, 2, 16, 256, 2>(G, bpt(Wb0 + q * 32768, wave * 2, lane), lane, dx1a);
      __syncthreads();  // P4q reads done -> G reusable
    }
    // ---- P4 epilogue: x1 += eta*clip(dx1a)  (RMW own cells of AX1)
#pragma unroll
    for (int rt = 0; rt < 2; ++rt)
#pragma unroll
      for (int ct = 0; ct < 2; ++ct) {
        int col = (wave * 2 + ct) * 16 + csub;
#pragma unroll
        for (int i = 0; i < 4; ++i) {
          int row = rt * 16 + rsub + i;
          int sb = (row * 512 + col * 2) ^ ((row & 7) << 4);
          float dx = fminf(1.f, fmaxf(-1.f, dx1a[rt * 2 + ct][i]));
          float x1o = (float)*(const _Float16*)(AX1 + sb);
          *(_Float16*)(AX1 + sb) = (_Float16)(x1o + ETA * dx);
        }
      }
    // ---- P5: dx2a += g1 @ W1^T (reads AG1 g1); ep: x2 RMW in AQ
    {
#pragma unroll
      for (int ct = 0; ct < 2; ++ct)
        mm_burst<2, 8, 1, 16, 512, 2>(AG1, bpt(Wb1, wave * 2 + ct, lane), lane, &dx2a[ct]);
#pragma unroll
      for (int rt = 0; rt < 2; ++rt)
#pragma unroll
        for (int ct = 0; ct < 2; ++ct) {
          int col = (wave * 2 + ct) * 16 + csub;
#pragma unroll
          for (int i = 0; i < 4; ++i) {
            int row = rt * 16 + rsub + i;
            int sb = (row * 512 + col * 2) ^ ((row & 7) << 4);
            float dx = fminf(1.f, fmaxf(-1.f, dx2a[rt * 2 + ct][i]));
            float x2o = (float)*(const _Float16*)(AQ + sb);
            *(_Float16*)(AQ + sb) = (_Float16)(x2o + ETA * dx);
          }
        }
    }
    __syncthreads();  // B7: all g1 reads done -> AG1 reusable for g2
    // ---- publish g2 into AG1
#pragma unroll
    for (int rt = 0; rt < 2; ++rt)
#pragma unroll
      for (int ct = 0; ct < 2; ++ct) {
        int col = (wave * 2 + ct) * 16 + csub;
#pragma unroll
        for (int i = 0; i < 4; ++i) {
          int row = rt * 16 + rsub + i;
          int sb = (row * 512 + col * 2) ^ ((row & 7) << 4);
          int li = (rt * 2 + ct) * 4 + i;
          *(_Float16*)(AG1 + sb) = g2h[li >> 3][li & 7];
        }
      }
    __syncthreads();  // B8: g2 published
    // ---- P6: dx3 = g2 @ W2^T (reads AG1); B9; ep: x3m += ; x3 image -> G
    {
      floatx4 acc6[2];
#pragma unroll
      for (int i = 0; i < 2; ++i) acc6[i] = zf;
      mm_burst<2, 8, 1, 8, 512, 1>(AG1, bpt(Wb2, wave, lane), lane, acc6);
      __syncthreads();  // B9: g2 reads done -> AG1 reusable next iter (P1-ep)
      int col = wave * 16 + csub;
#pragma unroll
      for (int rt = 0; rt < 2; ++rt)
#pragma unroll
        for (int i = 0; i < 4; ++i) {
          int row = rt * 16 + rsub + i;
          float dx = fminf(1.f, fmaxf(-1.f, acc6[rt][i]));
          float nv = x3m[rt][i] + ETA * dx;
          x3m[rt][i] = nv;
          int byte = (row * 256 + col * 2) ^ ((row & 7) << 4);
          *(_Float16*)(G + byte) = (_Float16)nv;
        }
    }
    __syncthreads();  // B10: x3 image published for next-iter P2
  }

  // write settled x3 (fp32 master)
  {
    int col = wave * 16 + csub;
#pragma unroll
    for (int rt = 0; rt < 2; ++rt)
#pragma unroll
      for (int i = 0; i < 4; ++i) {
        int row = rt * 16 + rsub + i;
        out[(size_t)(row0 + row) * D3 + col] = x3m[rt][i];
      }
  }
}

extern "C" void kernel_launch(void* const* d_in, const int* in_sizes, int n_in,
                              void* d_out, int out_size, void* d_ws, size_t ws_size,
                              hipStream_t stream) {
  const float* x0 = (const float*)d_in[0];
  const float* W0 = (const float*)d_in[1];
  const float* W1 = (const float*)d_in[2];
  const float* W2 = (const float*)d_in[3];
  float* out = (float*)d_out;

  _Float16* pack = (_Float16*)d_ws;
  const size_t pack_bytes = (size_t)PACK_ELEMS * 2;
  const size_t x0h_bytes = (size_t)NROWS * D0 * 2;
  int do_x0 = (ws_size >= pack_bytes + x0h_bytes) ? 1 : 0;
  _Float16* x0h = do_x0 ? (_Float16*)((char*)d_ws + pack_bytes) : nullptr;

  int total = PACK_ELEMS + (do_x0 ? NROWS * D0 : 0);
  repack_kernel<<<(total + 255) / 256, 256, 0, stream>>>(W0, W1, W2, x0, pack, x0h, do_x0);

  // 56 KB dynamic LDS -- below the 64 KB boundary, no attribute call needed;
  // two 512-thread blocks co-resident per CU (112 KB LDS, 16 waves).
  settle_kernel<<<NBLK, 512, 57344, stream>>>(x0, x0h, pack, out);
}